// Round 6
// baseline (537.850 us; speedup 1.0000x reference)
//
#include <hip/hip_runtime.h>
#include <hip/hip_bf16.h>

// ModulatedConv2d: B=16, Cin=Cout=512, H=W=64, 3x3, pad 1.
// out[b,o] = dscale[b,o] * conv2d(s[b,:]*x[b], weight)   (weights shared across batch)

constexpr float CONV_SCALE = 0.014731391274719738f;  // 1/sqrt(512*9)
constexpr float MOD_SCALE  = 0.04419417382415922f;   // 1/sqrt(512)

typedef short  bf16x8 __attribute__((ext_vector_type(8)));
typedef float  f32x4  __attribute__((ext_vector_type(4)));

__device__ __forceinline__ unsigned short f2bf(float f) {
  unsigned u = __float_as_uint(f);
  u += 0x7fffu + ((u >> 16) & 1u);           // round-to-nearest-even
  return (unsigned short)(u >> 16);
}

__device__ __forceinline__ void async16(const void* g, void* l) {
  __builtin_amdgcn_global_load_lds((const __attribute__((address_space(1))) unsigned int*)g,
                                   (__attribute__((address_space(3))) unsigned int*)l,
                                   16, 0, 0);
}

// ---------- kernel 1: wsq[o,i] = sum_taps w^2 ; wt2 = bf16(w) in MFMA-FRAGMENT order ----------
// wt2 frag layout: frag_id = (plane*16 + icstep)*32 + (o>>4), plane = kh*3+kw, icstep = ic>>5.
// Within a frag (512 shorts = 1KB): lane = ((ic>>3)&3)*16 + (o&15), elem = ic&7  -> matches the
// 16x16x32 A-operand mapping (lane l: row o = l&15, k = (l>>4)*8+e).  k_conv reads one frag as
// ONE fully-coalesced global_load_dwordx4 per wave (64 lanes x 16B = the whole 1KB frag).
__global__ void k_prepw(const float* __restrict__ w, float* __restrict__ wsq,
                        unsigned short* __restrict__ wt2) {
  __shared__ float Wl[2304];
  int t = threadIdx.x;
  size_t base = (size_t)blockIdx.x * 2304;
#pragma unroll
  for (int k = 0; k < 3; ++k) {
    int idx = t + k * 256;
    if (idx < 576) ((float4*)Wl)[idx] = ((const float4*)(w + base))[idx];
  }
  __syncthreads();
  int g = blockIdx.x * 256 + t;
  int ic = g & 511, o = g >> 9;
  int lane8 = ((ic >> 3) & 3) * 16 + (o & 15);
  float ssq = 0.f;
#pragma unroll
  for (int tap = 0; tap < 9; ++tap) {
    float v = Wl[t * 9 + tap];
    ssq += v * v;
    size_t fidx = (size_t)((tap * 16 + (ic >> 5)) * 32 + (o >> 4));
    wt2[fidx * 512 + lane8 * 8 + (ic & 7)] = f2bf(v);
  }
  wsq[o * 512 + ic] = ssq;
}

// ---------- kernel 2 (fused style+dscale): s[b,i] and dscale[b,o] ----------
__global__ void k_mod(const float* __restrict__ style, const float* __restrict__ mw,
                      const float* __restrict__ mb, const float* __restrict__ wsq,
                      float* __restrict__ s_out, float* __restrict__ dscale) {
  __shared__ float sl[512];
  int b = blockIdx.x, t = threadIdx.x;     // 16 blocks x 512 threads
  // phase 1: s[b,t] = style[b,:] . mw[t,:] * MOD_SCALE + mb[t]
  const float4* st = (const float4*)(style + b * 512);
  const float4* wr = (const float4*)(mw + t * 512);
  float acc = 0.f;
#pragma unroll 8
  for (int j = 0; j < 128; ++j) {
    float4 a = st[j], w4 = wr[j];
    acc += a.x * w4.x + a.y * w4.y + a.z * w4.z + a.w * w4.w;
  }
  float sv = acc * MOD_SCALE + mb[t];
  sl[t] = sv;
  s_out[b * 512 + t] = sv;
  __syncthreads();
  // phase 2: dscale[b,t] = rsqrt(CS^2 * sum_i wsq[t,i]*s[b,i]^2 + 1e-8) * CS
  const float4* sq = (const float4*)(wsq + t * 512);
  float a2 = 0.f;
#pragma unroll 8
  for (int j = 0; j < 128; ++j) {
    float4 q4 = sq[j];
    float4 s4 = *(const float4*)&sl[j * 4];
    a2 += q4.x * s4.x * s4.x + q4.y * s4.y * s4.y + q4.z * s4.z * s4.z + q4.w * s4.w * s4.w;
  }
  dscale[b * 512 + t] = rsqrtf(CONV_SCALE * CONV_SCALE * a2 + 1e-8f) * CONV_SCALE;
}

// ---------- kernel 3: xt[b][h+1][w][ic] = bf16(x[b][ic][h][w] * s[b][ic])  (NCHW->NHWC) ----------
// LDS-FREE register transpose (proven round 2/5).  zpad FUSED: blocks h==0 / h==63 also zero the
// halo rows 0 / 65 of their b (saves a dispatch).
__global__ void k_xt(const float* __restrict__ x, const float* __restrict__ s,
                     unsigned short* __restrict__ xt) {
  int h = blockIdx.x, b = blockIdx.y;
  int t = threadIdx.x;
  if (h == 0) {
    unsigned short* p = xt + (size_t)(b * 66) * 64 * 512;
    int4 z = {0, 0, 0, 0};
    for (int idx = t; idx < 4096; idx += 256) ((int4*)p)[idx] = z;
  } else if (h == 63) {
    unsigned short* p = xt + (size_t)(b * 66 + 65) * 64 * 512;
    int4 z = {0, 0, 0, 0};
    for (int idx = t; idx < 4096; idx += 256) ((int4*)p)[idx] = z;
  }
  const float* xp = x + (size_t)b * 512 * 4096 + h * 64;
  unsigned short* xo = xt + ((size_t)(b * 66 + h + 1) * 64) * 512;
  int o8 = t >> 4, wq = t & 15;              // ic-octet (0..15), w-quad (0..15)
  for (int ic0 = 0; ic0 < 512; ic0 += 128) {
    int icb = ic0 + o8 * 8;
    float4 v[8];
    float sc[8];
#pragma unroll
    for (int r = 0; r < 8; ++r) {
      v[r] = *(const float4*)&xp[(size_t)(icb + r) * 4096 + wq * 4];
      sc[r] = s[b * 512 + icb + r];
    }
#pragma unroll
    for (int j = 0; j < 4; ++j) {            // 4 w-values of this quad
      unsigned pk[4];
#pragma unroll
      for (int p = 0; p < 4; ++p) {
        float lo = ((const float*)&v[2 * p])[j]     * sc[2 * p];
        float hi = ((const float*)&v[2 * p + 1])[j] * sc[2 * p + 1];
        pk[p] = (unsigned)f2bf(lo) | ((unsigned)f2bf(hi) << 16);
      }
      *(uint4*)&xo[(size_t)(wq * 4 + j) * 512 + icb] = *(uint4*)pk;
    }
  }
}

// ---------- kernel 4: the conv (implicit GEMM, MFMA bf16, W-from-global) ----------
// Round-5 post-mortem: LDS(20.7K cy) + MFMA(22.3K cy) per CU-step ran fully SERIALIZED under
// every barrier scheme tried (49-51% MfmaUtil in rounds 0,1,5) — the shared FCFS LDS queue
// keeps all waves in lockstep, and at 42.7 FLOP/LDS-byte (breakeven 39.7) there's no slack.
// FIX: remove W from the LDS pipe.  W-fragments (72/wave/step, 2/3 of all LDS reads; identical
// across the 8 waves) are now loaded per-wave straight from global wt2 (pre-swizzled into
// fragment order -> one coalesced 1KB global_load_dwordx4 per frag; L2-hot XCD-pinned slice,
// L1 hits for 7 of 8 waves).  Register loads need NO barriers (per-wave vmcnt, compiler-
// managed) and the vmem pipe overlaps MFMA.  LDS keeps only X: 3.5K cy/CU-step << MFMA 11.2K.
// LDS 82.5KB (X dbuf only), 1 block/CU, 8 waves = 2/SIMD.  One barrier per step (X swap).
// acc[8][4] in AGPRs via intrinsic at __launch_bounds__(512,2) (proven: round-5 VGPR_Count=124).
__global__ __launch_bounds__(512, 2)
void k_conv(const unsigned short* __restrict__ xt, const unsigned short* __restrict__ wt2,
            const float* __restrict__ dscale, float* __restrict__ out) {
  __shared__ short Xs[2][10 * 66 * 32];   // 2 x 41.25 KB: [row(8+2 halo)][col(pad+64+pad)][ic32]

  // XCD-aware decode: XCD k (= lin%8) owns o-slice k>>1 -> its wt2 slice (1.18 MB) is
  // L2-resident per XCD.  Bijective for 512 blocks.
  const int lin = blockIdx.x;
  const int k8 = lin & 7, jj = lin >> 3;
  const int o0 = (k8 >> 1) * 128;
  const int b  = ((k8 & 1) << 3) | (jj >> 3);
  const int h0 = (jj & 7) * 8;
  const int t = threadIdx.x;
  const int wave = t >> 6, lane = t & 63;
  const int q = lane >> 4, l16 = lane & 15;

  const int xsrc8 = ((lane & 3) ^ ((((lane >> 2) + 1) >> 1) & 3)) * 8;
  const int fo = o0 >> 4;                  // W frag o-offset (0,8,16,24)

  f32x4 acc[8][4];
#pragma unroll
  for (int i = 0; i < 8; ++i)
#pragma unroll
    for (int j = 0; j < 4; ++j) acc[i][j] = (f32x4){0.f, 0.f, 0.f, 0.f};

  // zero halo columns (col 0 and 65) of all 10 rows, BOTH X buffers (whole 64B col-rows ->
  // swizzle-invariant: any chunk permutation of zeros is zeros)
  for (int z = t; z < 640; z += 512) {
    int bi = (z >= 320) ? 1 : 0;
    int zz = z - bi * 320;
    int r = zz >> 5, rem = zz & 31;
    int col = (rem >> 4) * 65, ch2 = (rem & 15) * 2;
    *(int*)&Xs[bi][(r * 66 + col) * 32 + ch2] = 0;
  }

  auto stageX = [&](int i_, int xb_) {
    int ic0_ = i_ * 32;
#pragma unroll
    for (int j2 = 0; j2 < 5; ++j2) {
      int c = wave * 5 + j2;                // 40 chunks: 10 rows x 4 col-quarters
      int row = c >> 2, q16 = c & 3;
      async16(xt + ((size_t)((b * 66 + h0 + row) * 64) + q16 * 16 + (lane >> 2)) * 512 + ic0_ + xsrc8,
              &Xs[xb_][(row * 66 + 1 + q16 * 16) * 32]);
    }
  };

  // prologue: X(0) into buffer 0; full drain (also makes the halo ds_writes visible).
  stageX(0, 0);
  __syncthreads();

  for (int i = 0; i < 16; ++i) {
    const int cur = i & 1;
    if (i < 15) stageX(i + 1, cur ^ 1);    // X(i+1) prefetch, certified by step-end barrier
    for (int kh = 0; kh < 3; ++kh) {
      const short* Xrow = &Xs[cur][(wave + kh) * 66 * 32];
#pragma unroll
      for (int kw = 0; kw < 3; ++kw) {
        // ---- A-operands: 8 W-frags straight from global (L1/L2), fully coalesced 1KB each
        const unsigned short* fp =
            wt2 + ((size_t)(((kh * 3 + kw) * 16 + i) * 32 + fo)) * 512 + lane * 8;
        bf16x8 af[8];
#pragma unroll
        for (int mi = 0; mi < 8; ++mi) af[mi] = *(const bf16x8*)&fp[mi * 512];
        // ---- B-operands: 4 X-frags from LDS (swizzled, conflict-free)
        bf16x8 bfr[4];
#pragma unroll
        for (int ni = 0; ni < 4; ++ni) {
          int c = ni * 16 + l16 + kw;
          bfr[ni] = *(const bf16x8*)&Xrow[c * 32 + ((q ^ ((c >> 1) & 3)) << 3)];
        }
        __builtin_amdgcn_s_setprio(1);
#pragma unroll
        for (int mi = 0; mi < 8; ++mi)
#pragma unroll
          for (int ni = 0; ni < 4; ++ni)
            acc[mi][ni] = __builtin_amdgcn_mfma_f32_16x16x32_bf16(af[mi], bfr[ni], acc[mi][ni], 0, 0, 0);
        __builtin_amdgcn_s_setprio(0);
      }
    }
    __syncthreads();                       // X(i+1) certified; Xs[cur] free for re-stage
  }

  // ---- epilogue: D[row=q*4+r][col=l16] per 16x16 frag; scale by dscale[b,o]
  const int h = h0 + wave;
#pragma unroll
  for (int mi = 0; mi < 8; ++mi)
#pragma unroll
    for (int r = 0; r < 4; ++r) {
      int o_l = mi * 16 + q * 4 + r;
      float ds = dscale[b * 512 + o0 + o_l];
      float* orow = out + ((size_t)(b * 512 + o0 + o_l) * 64 + h) * 64;
#pragma unroll
      for (int ni = 0; ni < 4; ++ni)
        orow[ni * 16 + l16] = acc[mi][ni][r] * ds;
    }
}

extern "C" void kernel_launch(void* const* d_in, const int* in_sizes, int n_in,
                              void* d_out, int out_size, void* d_ws, size_t ws_size,
                              hipStream_t stream) {
  const float* x      = (const float*)d_in[0];  // (16,512,64,64)
  const float* style  = (const float*)d_in[1];  // (16,512)
  const float* weight = (const float*)d_in[2];  // (1,512,512,3,3)
  const float* mw     = (const float*)d_in[3];  // (512,512)
  const float* mb     = (const float*)d_in[4];  // (512,)
  float* out = (float*)d_out;

  // workspace layout
  float* s      = (float*)d_ws;                       // 8192 f32
  float* dscale = s + 8192;                           // 8192 f32
  float* wsq    = dscale + 8192;                      // 262144 f32
  unsigned short* wt2 = (unsigned short*)(wsq + 262144);  // 9*512*512 bf16 = 4.5 MiB (frag order)
  unsigned short* xt = wt2 + 9 * 512 * 512;           // 16*66*64*512 bf16 = 66 MiB (2 halo rows/b)

  k_prepw<<<1024, 256, 0, stream>>>(weight, wsq, wt2);
  k_mod<<<16, 512, 0, stream>>>(style, mw, mb, wsq, s, dscale);
  k_xt<<<dim3(64, 16), 256, 0, stream>>>(x, s, xt);
  k_conv<<<512, 512, 0, stream>>>(xt, wt2, dscale, out);
}